// Round 1
// 343.726 us; speedup vs baseline: 1.0292x; 1.0292x over previous
//
#include <hip/hip_runtime.h>
#include <math.h>

typedef unsigned short u16;
typedef __attribute__((ext_vector_type(8))) short short8;     // 8 bf16 = one MFMA A/B frag
typedef __attribute__((ext_vector_type(4))) float floatx4;    // MFMA C/D frag
typedef __attribute__((ext_vector_type(4))) unsigned short ushort4v;
typedef __attribute__((ext_vector_type(2))) unsigned int uint2v;

// ---------- bf16 helpers (raw u16, RNE) ----------
__device__ __forceinline__ float bf2f(u16 x) {
    union { unsigned int u; float f; } v; v.u = ((unsigned int)x) << 16; return v.f;
}
__device__ __forceinline__ u16 f2bf(float f) {
    union { float f; unsigned int u; } v; v.f = f;
    unsigned int r = v.u + 0x7fffu + ((v.u >> 16) & 1u);
    return (u16)(r >> 16);
}
__device__ __forceinline__ unsigned int pk2bf(float a, float b) {
#if __has_builtin(__builtin_amdgcn_cvt_pk_bf16_f32)
    auto r = __builtin_amdgcn_cvt_pk_bf16_f32(a, b);
    union { decltype(r) v; unsigned int u; } cv; cv.v = r; return cv.u;
#else
    return (unsigned int)f2bf(a) | ((unsigned int)f2bf(b) << 16);
#endif
}

// ---------- cross-lane reg-bit <-> lane-bit swaps ----------
// swap32: exchanges reg-index bit with lane bit5.
// result: (x0', x1') with x0' = {x0.lo32, x1.lo32}, x1' = {x0.hi32, x1.hi32}
__device__ __forceinline__ void swap32(unsigned int& x0, unsigned int& x1, int lane) {
#if __has_builtin(__builtin_amdgcn_permlane32_swap)
    (void)lane;
    auto r = __builtin_amdgcn_permlane32_swap((int)x0, (int)x1, false, false);
    x0 = (unsigned int)r[0]; x1 = (unsigned int)r[1];
#else
    const bool hi = (lane & 32) != 0;
    const unsigned int s = hi ? x0 : x1;
    const unsigned int rr = (unsigned int)__shfl_xor((int)s, 32, 64);
    const unsigned int n0 = hi ? rr : x0;
    const unsigned int n1 = hi ? x1 : rr;
    x0 = n0; x1 = n1;
#endif
}
// swap16: exchanges reg-index bit with lane bit4 (within each 32-lane half).
__device__ __forceinline__ void swap16(unsigned int& x0, unsigned int& x1, int lane) {
#if __has_builtin(__builtin_amdgcn_permlane16_swap)
    (void)lane;
    auto r = __builtin_amdgcn_permlane16_swap((int)x0, (int)x1, false, false);
    x0 = (unsigned int)r[0]; x1 = (unsigned int)r[1];
#else
    const bool hi = (lane & 16) != 0;
    const unsigned int s = hi ? x0 : x1;
    const unsigned int rr = (unsigned int)__shfl_xor((int)s, 16, 64);
    const unsigned int n0 = hi ? rr : x0;
    const unsigned int n1 = hi ? x1 : rr;
    x0 = n0; x1 = n1;
#endif
}

// async global -> LDS, 16B per lane
__device__ __forceinline__ void g2l16(const u16* g, u16* l) {
    __builtin_amdgcn_global_load_lds(
        (const __attribute__((address_space(1))) void*)g,
        (__attribute__((address_space(3))) void*)l, 16, 0, 0);
}

// =====================================================================
// wfuse: w_z[row] = dot(W_z[row][:], wv_z[:]) ; block x==0 also emits
// bdot[z] = dot(bl_z, wv_z).  grid (64, 4).
// =====================================================================
struct WFuseJobs { const float* W[4]; const float* wv[4]; const float* bl[4];
                   float* out[4]; float* bdot; };

__global__ __launch_bounds__(256) void wfuse(WFuseJobs wf) {
    const int z = blockIdx.y;
    const float* W = wf.W[z];
    const float* wv = wf.wv[z];
    float* out = wf.out[z];
    const int t = threadIdx.x;
    const int lane = t & 63, w = t >> 6;
#pragma unroll
    for (int i = 0; i < 4; i++) {
        const int row = blockIdx.x * 16 + w * 4 + i;
        const float* Wr = W + (size_t)row * 1024 + lane * 16;
        const float* vr = wv + lane * 16;
        float p = 0.f;
#pragma unroll
        for (int c = 0; c < 4; c++) {
            const floatx4 a = *(const floatx4*)(Wr + c * 4);
            const floatx4 b = *(const floatx4*)(vr + c * 4);
            p += a[0] * b[0] + a[1] * b[1] + a[2] * b[2] + a[3] * b[3];
        }
#pragma unroll
        for (int m = 1; m <= 32; m <<= 1) p += __shfl_xor(p, m);
        if (lane == 0) out[row] = p;
    }
    if (blockIdx.x == 0) {
        const floatx4 bb = *(const floatx4*)(wf.bl[z] + t * 4);
        const floatx4 vv = *(const floatx4*)(wv + t * 4);
        float p = bb[0] * vv[0] + bb[1] * vv[1] + bb[2] * vv[2] + bb[3] * vv[3];
#pragma unroll
        for (int m = 1; m <= 32; m <<= 1) p += __shfl_xor(p, m);
        __shared__ float red[4];
        if ((t & 63) == 0) red[t >> 6] = p;
        __syncthreads();
        if (t == 0) wf.bdot[z] = red[0] + red[1] + red[2] + red[3];
    }
}

// =====================================================================
// gatecast: per row m, z<2: lam = sigmoid(xa.w1 + xc.w2 + consts);
//   write A'[m] = [(1-lam)*xa | lam*xc] bf16 (concat-K layout, stride 2048)
//   and lam[m] for the GEMM epilogue bias mix.
// z==2: plain cast vx -> bf16 (stride 1024).
// grid (4096, 3), block 256, 4 elems/thread.
// =====================================================================
struct GCJobs {
    const float* xa[3]; const float* xc[3];
    const float* w1[3]; const float* w2[3];
    const float* bdot;                 // 4 scalars
    const float* sA[3]; const float* sB[3];
    float* lamout[3];
    u16* dst[3];
};

__global__ __launch_bounds__(256) void gatecast(GCJobs gj) {
    const int z = blockIdx.y;
    const int row = blockIdx.x;
    const int t = threadIdx.x;
    const size_t off = (size_t)row * 1024 + t * 4;
    const floatx4 a = *(const floatx4*)(gj.xa[z] + off);

    if (z == 2) {
        ushort4v o;
        const unsigned int lo = pk2bf(a[0], a[1]);
        const unsigned int hi = pk2bf(a[2], a[3]);
        o[0] = (u16)(lo & 0xffff); o[1] = (u16)(lo >> 16);
        o[2] = (u16)(hi & 0xffff); o[3] = (u16)(hi >> 16);
        *(ushort4v*)(gj.dst[2] + (size_t)row * 1024 + t * 4) = o;
        return;
    }

    const floatx4 c  = *(const floatx4*)(gj.xc[z] + off);
    const floatx4 w1 = *(const floatx4*)(gj.w1[z] + t * 4);
    const floatx4 w2 = *(const floatx4*)(gj.w2[z] + t * 4);
    float p = 0.f;
#pragma unroll
    for (int j = 0; j < 4; j++) p += a[j] * w1[j] + c[j] * w2[j];
#pragma unroll
    for (int m = 1; m <= 32; m <<= 1) p += __shfl_xor(p, m);
    __shared__ float red[4];
    if ((t & 63) == 0) red[t >> 6] = p;
    __syncthreads();
    const float x = red[0] + red[1] + red[2] + red[3]
                  + gj.bdot[2 * z] + gj.bdot[2 * z + 1]
                  + gj.sA[z][0] + gj.sB[z][0];
    const float lam = 1.f / (1.f + exp2f(-x * 1.44269504f));
    if (t == 0) gj.lamout[z][row] = lam;
    const float oml = 1.f - lam;

    u16* d = gj.dst[z] + (size_t)row * 2048 + t * 4;
    ushort4v o1, o2;
    {
        const unsigned int lo = pk2bf(oml * a[0], oml * a[1]);
        const unsigned int hi = pk2bf(oml * a[2], oml * a[3]);
        o1[0] = (u16)(lo & 0xffff); o1[1] = (u16)(lo >> 16);
        o1[2] = (u16)(hi & 0xffff); o1[3] = (u16)(hi >> 16);
    }
    {
        const unsigned int lo = pk2bf(lam * c[0], lam * c[1]);
        const unsigned int hi = pk2bf(lam * c[2], lam * c[3]);
        o2[0] = (u16)(lo & 0xffff); o2[1] = (u16)(lo >> 16);
        o2[2] = (u16)(hi & 0xffff); o2[3] = (u16)(hi >> 16);
    }
    *(ushort4v*)d = o1;
    *(ushort4v*)(d + 1024) = o2;
}

// =====================================================================
// wtrans: W[k][n] fp32 -> Wt[n*stride + koff + k] bf16 (concat-K capable)
// =====================================================================
struct WTJobs { const float* src[6]; u16* dst[6]; int stride[6]; int koff[6]; };

__global__ __launch_bounds__(256) void wtrans(WTJobs wj) {
    __shared__ float tile[32][33];
    const int z = blockIdx.z;
    const float* W = wj.src[z];
    u16* Wt = wj.dst[z];
    const int stride = wj.stride[z], koff = wj.koff[z];
    const int n0 = blockIdx.x * 32, k0 = blockIdx.y * 32;
    const int tx = threadIdx.x & 31, ty = threadIdx.x >> 5;
#pragma unroll
    for (int i = 0; i < 4; i++)
        tile[ty + i * 8][tx] = W[(size_t)(k0 + ty + i * 8) * 1024 + n0 + tx];
    __syncthreads();
#pragma unroll
    for (int i = 0; i < 4; i++)
        Wt[(size_t)(n0 + ty + i * 8) * stride + koff + k0 + tx] = f2bf(tile[tx][ty + i * 8]);
}

// =====================================================================
// transpose V: V[s][base+d] (stride 2048) -> Vtg[(bh*64+d)*2048 + s], bf16
// =====================================================================
__global__ __launch_bounds__(256) void vtrans(const u16* __restrict__ V,
                                              u16* __restrict__ Vtg) {
    __shared__ u16 tile[32][34];
    const int bh = blockIdx.z, b = bh >> 4, h = bh & 15;
    const int base = b * 1024 + h * 64;
    const int s0 = blockIdx.x * 32, d0 = blockIdx.y * 32;
    const int tx = threadIdx.x & 31, ty = threadIdx.x >> 5;
#pragma unroll
    for (int i = 0; i < 4; i++)
        tile[ty + i * 8][tx] = V[(size_t)(s0 + ty + i * 8) * 2048 + base + d0 + tx];
    __syncthreads();
#pragma unroll
    for (int i = 0; i < 4; i++)
        Vtg[((size_t)bh * 64 + d0 + ty + i * 8) * 2048 + s0 + tx] = tile[tx][ty + i * 8];
}

// =====================================================================
// projall v3: single-accumulator GEMM, concat-K inputs, bf16 reg-prefetch.
// out_bf16[M,1024] = A[M,K] @ Bt[1024][K] (+ epilogue bias / lam-bias-mix)
// 128x128 tile, BK=32. grid (8, 32, 3): z=0 q (K=2048), z=1 k (K=2048),
// z=2 v (K=1024). LDS 16 KB, 3 blocks/CU.
// =====================================================================
struct PJob {
    const u16* A; const u16* Bt; int K;
    const float* biasA; const float* biasC; const float* lam; u16* out;
};
struct PJobs { PJob j[3]; };

__global__ __launch_bounds__(256, 3) void projall(PJobs jobs) {
    __shared__ u16 As[128 * 32];
    __shared__ u16 Bs[128 * 32];
    const PJob jb = jobs.j[blockIdx.z];
    const int K = jb.K;
    const int m0 = blockIdx.y * 128;
    const int n0 = blockIdx.x * 128;
    const int t = threadIdx.x;
    const int lane = t & 63;
    const int wid = t >> 6;
    const int wm = wid >> 1, wn = wid & 1;
    const int qd = lane >> 4, lm = lane & 15;

    const floatx4 zero4 = {0.f, 0.f, 0.f, 0.f};
    floatx4 acc[4][4];
#pragma unroll
    for (int i = 0; i < 4; i++)
#pragma unroll
        for (int j2 = 0; j2 < 4; j2++) acc[i][j2] = zero4;

    // staging: thread t covers row = t>>1, cols colb..colb+15 (16 u16 = 2x16B)
    const int srow = t >> 1, colb = (t & 1) * 16;
    const u16* Ap = jb.A + (size_t)(m0 + srow) * K + colb;
    const u16* Bp = jb.Bt + (size_t)(n0 + srow) * K + colb;
    u16* awr = &As[srow * 32 + colb];
    u16* bwr = &Bs[srow * 32 + colb];

    short8 pa0 = *(const short8*)Ap;
    short8 pa1 = *(const short8*)(Ap + 8);
    short8 pb0 = *(const short8*)Bp;
    short8 pb1 = *(const short8*)(Bp + 8);

    for (int k0 = 0; k0 < K; k0 += 32) {
        __syncthreads();
        *(short8*)awr       = pa0;
        *(short8*)(awr + 8) = pa1;
        *(short8*)bwr       = pb0;
        *(short8*)(bwr + 8) = pb1;
        if (k0 + 32 < K) {
            Ap += 32; Bp += 32;
            pa0 = *(const short8*)Ap;
            pa1 = *(const short8*)(Ap + 8);
            pb0 = *(const short8*)Bp;
            pb1 = *(const short8*)(Bp + 8);
        }
        __syncthreads();

        short8 af[4], bfg[4];
#pragma unroll
        for (int i = 0; i < 4; i++) {
            af[i]  = *(const short8*)&As[(wm * 64 + i * 16 + lm) * 32 + qd * 8];
            bfg[i] = *(const short8*)&Bs[(wn * 64 + i * 16 + lm) * 32 + qd * 8];
        }
#pragma unroll
        for (int i = 0; i < 4; i++)
#pragma unroll
            for (int j2 = 0; j2 < 4; j2++)
                acc[i][j2] = __builtin_amdgcn_mfma_f32_16x16x32_bf16(af[i], bfg[j2], acc[i][j2], 0, 0, 0);
    }

#pragma unroll
    for (int i = 0; i < 4; i++) {
        const int mb = m0 + wm * 64 + i * 16 + qd * 4;
        float lamv[4];
        if (jb.lam) {
#pragma unroll
            for (int r = 0; r < 4; r++) lamv[r] = jb.lam[mb + r];
        }
#pragma unroll
        for (int j2 = 0; j2 < 4; j2++) {
            const int col = n0 + wn * 64 + j2 * 16 + lm;
            const float bA = jb.biasA[col];
            if (jb.lam) {
                const float dB = jb.biasC[col] - bA;
#pragma unroll
                for (int r = 0; r < 4; r++)
                    jb.out[(size_t)(mb + r) * 1024 + col] = f2bf(acc[i][j2][r] + bA + lamv[r] * dB);
            } else {
#pragma unroll
                for (int r = 0; r < 4; r++)
                    jb.out[(size_t)(mb + r) * 1024 + col] = f2bf(acc[i][j2][r] + bA);
            }
        }
    }
}

// =====================================================================
// gemm64: C_f32[M,1024] = A_bf16[M,1024] @ Bt[1024][1024] + bias
// 64x128 tile -> grid (8, 64) = 512 blocks. 12 KB LDS.
// =====================================================================
__global__ __launch_bounds__(256, 4) void gemm64(const u16* __restrict__ A,
                                                 const u16* __restrict__ Bt,
                                                 const float* __restrict__ bias,
                                                 float* __restrict__ C) {
    __shared__ u16 As[64 * 32];
    __shared__ u16 Bs[128 * 32];
    const int K = 1024;
    const int m0 = blockIdx.y * 64;
    const int n0 = blockIdx.x * 128;
    const int t = threadIdx.x;
    const int lane = t & 63;
    const int wid = t >> 6;
    const int wm = wid >> 1, wn = wid & 1;
    const int qd = lane >> 4, lm = lane & 15;

    const floatx4 zero4 = {0.f, 0.f, 0.f, 0.f};
    floatx4 acc[2][4];
#pragma unroll
    for (int i = 0; i < 2; i++)
#pragma unroll
        for (int j2 = 0; j2 < 4; j2++) acc[i][j2] = zero4;

    const int ar = t >> 2, ac_ = (t & 3) * 8;
    const int br = t >> 1, bc_ = (t & 1) * 16;
    const u16* Ap = A + (size_t)(m0 + ar) * K + ac_;
    const u16* Bp = Bt + (size_t)(n0 + br) * K + bc_;
    u16* awr = &As[ar * 32 + ac_];
    u16* bwr = &Bs[br * 32 + bc_];

    short8 pa0, pb0, pb1;
    pa0 = *(const short8*)Ap;
    pb0 = *(const short8*)Bp; pb1 = *(const short8*)(Bp + 8);

    for (int k0 = 0; k0 < K; k0 += 32) {
        __syncthreads();
        *(short8*)awr = pa0;
        *(short8*)bwr = pb0;
        *(short8*)(bwr + 8) = pb1;
        if (k0 + 32 < K) {
            Ap += 32; Bp += 32;
            pa0 = *(const short8*)Ap;
            pb0 = *(const short8*)Bp; pb1 = *(const short8*)(Bp + 8);
        }
        __syncthreads();

        short8 af[2], bfg[4];
#pragma unroll
        for (int i = 0; i < 2; i++)
            af[i] = *(const short8*)&As[(wm * 32 + i * 16 + lm) * 32 + qd * 8];
#pragma unroll
        for (int j2 = 0; j2 < 4; j2++)
            bfg[j2] = *(const short8*)&Bs[(wn * 64 + j2 * 16 + lm) * 32 + qd * 8];
#pragma unroll
        for (int i = 0; i < 2; i++)
#pragma unroll
            for (int j2 = 0; j2 < 4; j2++)
                acc[i][j2] = __builtin_amdgcn_mfma_f32_16x16x32_bf16(af[i], bfg[j2], acc[i][j2], 0, 0, 0);
    }

#pragma unroll
    for (int i = 0; i < 2; i++) {
        const int mb = m0 + wm * 32 + i * 16 + qd * 4;
#pragma unroll
        for (int j2 = 0; j2 < 4; j2++) {
            const int col = n0 + wn * 64 + j2 * 16 + lm;
            const float bv = bias[col];
#pragma unroll
            for (int r = 0; r < 4; r++)
                C[(size_t)(mb + r) * 1024 + col] = acc[i][j2][r] + bv;
        }
    }
}

// =====================================================================
// attention v5: split-K flash.
//  - 32 q-rows/wave, 4 waves/block (128 q-rows), grid (16 qtiles, 32 bh, 2 sp)
//    = 1024 blocks -> 4 blocks/CU (32 KB LDS, VGPR<=128).
//  - K/V staged via global_load_lds into XOR-swizzled linear LDS
//    (linear dest + pre-swizzled per-lane SOURCE + swizzled reads),
//    double-buffered, ONE barrier per K-tile.
//  - P never touches LDS: scores -> bf16 (cvt_pk) -> permlane32/16 swaps
//    rearrange lane-held kv groups into the PV A-fragment layout.
//  - bijective XCD swizzle: all 16 qtiles of one (bh,sp) share bid%8.
// =====================================================================
__global__ __launch_bounds__(256, 4) void attn5(
    const u16* __restrict__ Q, const u16* __restrict__ Kk,
    const u16* __restrict__ Vtg, float* __restrict__ ctxp,
    float* __restrict__ lp) {
    __shared__ __align__(16) u16 SB[16384];   // [2 bufs][K 64x64 | V 64x64] bf16

    // XCD-colocating bijective swizzle (nwg = 1024, 8 XCDs)
    const int bid = blockIdx.x + 16 * (blockIdx.y + 32 * blockIdx.z);
    const int sw = (bid & 7) * 128 + (bid >> 3);
    const int qt = sw & 15;
    const int bh = (sw >> 4) & 31;
    const int sp = sw >> 9;
    const int b = bh >> 4, h = bh & 15;
    const int hb = b * 1024 + h * 64;

    const int t = threadIdx.x, lane = t & 63, w = t >> 6;
    const int qd = lane >> 4, lm = lane & 15;
    const int q0w = qt * 128 + w * 32;

    // Q fragments (B operand of swapped QK^T): 2 qh blocks x 2 k-chunks
    short8 qf[2][2];
#pragma unroll
    for (int qh = 0; qh < 2; qh++) {
        const u16* qr = Q + (size_t)(q0w + qh * 16 + lm) * 2048 + hb;
#pragma unroll
        for (int c = 0; c < 2; c++)
            qf[qh][c] = *(const short8*)(qr + c * 32 + qd * 8);
    }

    const floatx4 zero4 = {0.f, 0.f, 0.f, 0.f};
    floatx4 ctx[2][4];
#pragma unroll
    for (int qh = 0; qh < 2; qh++)
#pragma unroll
        for (int g = 0; g < 4; g++) ctx[qh][g] = zero4;
    float lpart[2] = {0.f, 0.f};

    // staging: wave w stages K rows w*16..w*16+15 and V rows (d) w*16..w*16+15.
    // lane i -> LDS (row i>>3, 16B-unit i&7); source unit pre-swizzled so that
    // LDS holds unit_phys = unit_logical ^ (row&7).
    const int rl = lane >> 3;               // 0..7
    const int cuz = (lane & 7) ^ rl;        // swizzled source 16B-unit
    const u16* kp = Kk + (size_t)(sp * 1024 + w * 16 + rl) * 2048 + hb + cuz * 8;
    const u16* vp = Vtg + ((size_t)bh * 64 + w * 16 + rl) * 2048 + sp * 1024 + cuz * 8;
    u16* kd = &SB[(w * 16) * 64];
    u16* vd = &SB[4096 + (w * 16) * 64];

    // swizzled LDS read offsets (u16 units): row=lm within g-block, c chunk
    const int rdA = lm * 64 + ((qd ^ (lm & 7)) << 3);   // c=0
    const int rdB = rdA ^ 32;                            // c=1 (unit ^ 4)

    const float C = 0.18033688011112042f;   // log2(e)/sqrt(64)

#define STAGE(BUF) do {                                             \
        g2l16(kp,            kd + (BUF) * 8192);                    \
        g2l16(kp + 8 * 2048, kd + (BUF) * 8192 + 8 * 64);           \
        g2l16(vp,            vd + (BUF) * 8192);                    \
        g2l16(vp + 8 * 2048, vd + (BUF) * 8192 + 8 * 64);           \
        kp += 64 * 2048; vp += 64;                                  \
    } while (0)

#define COMPUTE(BUF) do {                                                          \
        short8 pa[2][2];                                                           \
        _Pragma("unroll")                                                          \
        for (int gp = 0; gp < 2; gp++) {                                           \
            unsigned int pw[2][2][2];                                              \
            _Pragma("unroll")                                                      \
            for (int g0 = 0; g0 < 2; g0++) {                                       \
                const int g = gp * 2 + g0;                                         \
                const short8 kf0 = *(const short8*)&SB[(BUF) * 8192 + g * 1024 + rdA]; \
                const short8 kf1 = *(const short8*)&SB[(BUF) * 8192 + g * 1024 + rdB]; \
                _Pragma("unroll")                                                  \
                for (int qh = 0; qh < 2; qh++) {                                   \
                    floatx4 st = zero4;                                            \
                    st = __builtin_amdgcn_mfma_f32_16x16x32_bf16(kf0, qf[qh][0], st, 0, 0, 0); \
                    st = __builtin_amdgcn_mfma_f32_16x16x32_bf16(kf1, qf[qh][1], st, 0, 0, 0); \
                    const float e0 = exp2f(st[0] * C), e1 = exp2f(st[1] * C);      \
                    const float e2 = exp2f(st[2] * C), e3 = exp2f(st[3] * C);      \
                    lpart[qh] += (e0 + e1) + (e2 + e3);                            \
                    pw[qh][g0][0] = pk2bf(e0, e1);                                 \
                    pw[qh][g0][1] = pk2bf(e2, e3);                                 \
                }                                                                  \
            }                                                                      \
            _Pragma("unroll")                                                      \
            for (int qh = 0; qh < 2; qh++) {                                       \
                unsigned int a0 = pw[qh][0][0], b0 = pw[qh][1][0];                 \
                unsigned int a1 = pw[qh][0][1], b1 = pw[qh][1][1];                 \
                swap32(a0, b0, lane); swap32(a1, b1, lane);                        \
                swap16(a0, b0, lane); swap16(a1, b1, lane);                        \
                union { unsigned int u[4]; short8 s; } cv;                         \
                cv.u[0] = a0; cv.u[1] = a1; cv.u[2] = b0; cv.u[3] = b1;            \
                pa[qh][gp] = cv.s;                                                 \
            }                                                                      \
        }                                                                          \
        __builtin_amdgcn_s_setprio(1);                                             \
        _Pragma("unroll")                                                          \
        for (int g = 0; g < 4; g++) {                                              \
            const short8 vb0 = *(const short8*)&SB[(BUF) * 8192 + 4096 + g * 1024 + rdA]; \
            const short8 vb1 = *(const short8*)&SB[(BUF) * 8192 + 4096 + g * 1024 + rdB]; \
            _Pragma("unroll")                                                      \
            for (int qh = 0; qh < 2; qh++) {                                       \
                ctx[qh][g] = __builtin_amdgcn_mfma_f32_16x16x32_bf16(pa[qh][0], vb0, ctx[qh][g], 0, 0, 0); \
                ctx[qh][g] = __builtin_amdgcn_mfma_f32_16x16x32_bf16(pa[qh][1], vb1, ctx[qh][g], 0, 0, 0); \
            }                                                                      \
        }                                                                          \
        __builtin_amdgcn_s_setprio(0);                                             \
    } while (0)

    STAGE(0);   // prologue: kt = 0 -> buf0
#pragma unroll 1
    for (int it = 0; it < 8; it++) {
        __syncthreads();            // buf0 ready (vmcnt drained); buf1 reads done
        STAGE(1);                   // prefetch kt = 2*it+1 -> buf1
        COMPUTE(0);                 // kt = 2*it from buf0
        __syncthreads();            // buf1 ready; buf0 reads done
        if (it < 7) STAGE(0);       // prefetch kt = 2*it+2 -> buf0
        COMPUTE(1);                 // kt = 2*it+1 from buf1
    }
#undef STAGE
#undef COMPUTE

    float* cbase = ctxp + (size_t)sp * 4194304;
#pragma unroll
    for (int qh = 0; qh < 2; qh++) {
        float l = lpart[qh];
        l += __shfl_xor(l, 16);
        l += __shfl_xor(l, 32);
        if (lane < 16)
            lp[(size_t)sp * 65536 + bh * 2048 + q0w + qh * 16 + lane] = l;
#pragma unroll
        for (int r = 0; r < 4; r++) {
            const int srow = q0w + qh * 16 + qd * 4 + r;
            float* orow = cbase + (size_t)srow * 2048 + hb;
#pragma unroll
            for (int g = 0; g < 4; g++)
                orow[g * 16 + lm] = ctx[qh][g][r];
        }
    }
}

// =====================================================================
// merge: out_bf16 = (ctx0 + ctx1) / (l0 + l1), elementwise over 4M
// =====================================================================
__global__ __launch_bounds__(256) void merge(const float* __restrict__ ctxp,
                                             const float* __restrict__ lp,
                                             u16* __restrict__ out) {
    const size_t idx = ((size_t)blockIdx.x * 256 + threadIdx.x) * 4;
    const floatx4 a = *(const floatx4*)(ctxp + idx);
    const floatx4 c = *(const floatx4*)(ctxp + 4194304 + idx);
    const int srow = (int)(idx >> 11);
    const int rem = (int)(idx & 2047);
    const int bh = rem >> 6;
    const float l = lp[bh * 2048 + srow] + lp[65536 + bh * 2048 + srow];
    const float inv = 1.0f / l;
    ushort4v o;
    const unsigned int lo = pk2bf((a[0] + c[0]) * inv, (a[1] + c[1]) * inv);
    const unsigned int hi = pk2bf((a[2] + c[2]) * inv, (a[3] + c[3]) * inv);
    o[0] = (u16)(lo & 0xffff); o[1] = (u16)(lo >> 16);
    o[2] = (u16)(hi & 0xffff); o[3] = (u16)(hi >> 16);
    *(ushort4v*)(out + idx) = o;
}

// =====================================================================
// host orchestration
// =====================================================================
extern "C" void kernel_launch(void* const* d_in, const int* in_sizes, int n_in,
                              void* d_out, int out_size, void* d_ws, size_t ws_size,
                              hipStream_t stream) {
    const float* qx = (const float*)d_in[0];
    const float* kx = (const float*)d_in[1];
    const float* vx = (const float*)d_in[2];
    const float* qc = (const float*)d_in[3];
    const float* kc = (const float*)d_in[4];
    const float* W_qx = (const float*)d_in[5];   const float* b_qx = (const float*)d_in[6];
    const float* W_kx = (const float*)d_in[7];   const float* b_kx = (const float*)d_in[8];
    const float* W_vx = (const float*)d_in[9];   const float* b_vx = (const float*)d_in[10];
    const float* W_qc = (const float*)d_in[11];  const float* b_qc = (const float*)d_in[12];
    const float* W_kc = (const float*)d_in[13];  const float* b_kc = (const float*)d_in[14];
    const float* W_out = (const float*)d_in[15]; const float* b_out = (const float*)d_in[16];
    const float* W_Vqx = (const float*)d_in[17]; const float* b_Vqx = (const float*)d_in[18];
    const float* W_Vqc = (const float*)d_in[19]; const float* b_Vqc = (const float*)d_in[20];
    const float* W_Vkx = (const float*)d_in[21]; const float* b_Vkx = (const float*)d_in[22];
    const float* W_Vkc = (const float*)d_in[23]; const float* b_Vkc = (const float*)d_in[24];

    char* ws = (char*)d_ws;
    const size_t MB = 1048576;
    // layout (aliases):
    //   0  .. 16 MB : Aq (concat-K q input)   | later ctxp[0] (fp32 partial 0)
    //   16 .. 32 MB : Ak                      | later ctxp[1]
    //   32 .. 40 MB : Av                      | later Vtg
    //   40 .. 44 MB : Wtq (1024 x 2048 bf16)
    //   44 .. 48 MB : Wtk
    //   48 .. 50 MB : Wtv (1024 x 1024 bf16)
    //   50 .. 52 MB : Wto
    //   52 .. 60 MB : Pv
    //   60 .. 68 MB : qg
    //   68 .. 76 MB : kg
    //   76 .. 84 MB : ctxbf
    //   84 MB+ : wfused 16KB, bdot, lam 32KB, l_part 512KB
    u16* Aq  = (u16*)ws;
    u16* Ak  = (u16*)(ws + 16 * MB);
    u16* Av  = (u16*)(ws + 32 * MB);
    u16* Wtq = (u16*)(ws + 40 * MB);
    u16* Wtk = (u16*)(ws + 44 * MB);
    u16* Wtv = (u16*)(ws + 48 * MB);
    u16* Wto = (u16*)(ws + 50 * MB);
    u16* Pv    = (u16*)(ws + 52 * MB);
    u16* qg    = (u16*)(ws + 60 * MB);
    u16* kg    = (u16*)(ws + 68 * MB);
    u16* ctxbf = (u16*)(ws + 76 * MB);
    float* wfused = (float*)(ws + 84 * MB);                       // 4 x 1024
    float* bdot   = (float*)(ws + 84 * MB + 16384);               // 4 scalars
    float* lam    = (float*)(ws + 84 * MB + 16384 + 256);         // 2 x 4096
    float* l_part = (float*)(ws + 84 * MB + 16384 + 256 + 32768); // 2 x 32 x 2048
    float* ctxp = (float*)ws;                  // aliases Aq/Ak (dead after projall)
    u16* Vtg    = (u16*)(ws + 32 * MB);        // aliases Av (dead after projall)

    // 1. fused gating weight vectors + bias-dot consts
    WFuseJobs wf;
    wf.W[0] = W_qx; wf.wv[0] = W_Vqx; wf.bl[0] = b_qx; wf.out[0] = wfused;
    wf.W[1] = W_qc; wf.wv[1] = W_Vqc; wf.bl[1] = b_qc; wf.out[1] = wfused + 1024;
    wf.W[2] = W_kx; wf.wv[2] = W_Vkx; wf.bl[2] = b_kx; wf.out[2] = wfused + 2048;
    wf.W[3] = W_kc; wf.wv[3] = W_Vkc; wf.bl[3] = b_kc; wf.out[3] = wfused + 3072;
    wf.bdot = bdot;
    wfuse<<<dim3(64, 4), 256, 0, stream>>>(wf);

    // 2. gatecast: lambdas + scaled concat-K bf16 A matrices + v cast
    GCJobs gj;
    gj.xa[0] = qx; gj.xc[0] = qc; gj.w1[0] = wfused;        gj.w2[0] = wfused + 1024;
    gj.sA[0] = b_Vqx; gj.sB[0] = b_Vqc; gj.lamout[0] = lam;        gj.dst[0] = Aq;
    gj.xa[1] = kx; gj.xc[1] = kc; gj.w1[1] = wfused + 2048; gj.w2[1] = wfused + 3072;
    gj.sA[1] = b_Vkx; gj.sB[1] = b_Vkc; gj.lamout[1] = lam + 4096; gj.dst[1] = Ak;
    gj.xa[2] = vx; gj.xc[2] = nullptr; gj.w1[2] = nullptr; gj.w2[2] = nullptr;
    gj.sA[2] = nullptr; gj.sB[2] = nullptr; gj.lamout[2] = nullptr; gj.dst[2] = Av;
    gj.bdot = bdot;
    gatecast<<<dim3(4096, 3), 256, 0, stream>>>(gj);

    // 3. transpose + cast weights into concat-K layouts
    WTJobs wj;
    wj.src[0] = W_qx; wj.dst[0] = Wtq; wj.stride[0] = 2048; wj.koff[0] = 0;
    wj.src[1] = W_qc; wj.dst[1] = Wtq; wj.stride[1] = 2048; wj.koff[1] = 1024;
    wj.src[2] = W_kx; wj.dst[2] = Wtk; wj.stride[2] = 2048; wj.koff[2] = 0;
    wj.src[3] = W_kc; wj.dst[3] = Wtk; wj.stride[3] = 2048; wj.koff[3] = 1024;
    wj.src[4] = W_vx; wj.dst[4] = Wtv; wj.stride[4] = 1024; wj.koff[4] = 0;
    wj.src[5] = W_out; wj.dst[5] = Wto; wj.stride[5] = 1024; wj.koff[5] = 0;
    wtrans<<<dim3(32, 32, 6), 256, 0, stream>>>(wj);

    // 4. projections: q (K=2048), k (K=2048), v (K=1024) in one launch
    PJobs pj;
    pj.j[0].A = Aq; pj.j[0].Bt = Wtq; pj.j[0].K = 2048;
    pj.j[0].biasA = b_qx; pj.j[0].biasC = b_qc; pj.j[0].lam = lam;        pj.j[0].out = qg;
    pj.j[1].A = Ak; pj.j[1].Bt = Wtk; pj.j[1].K = 2048;
    pj.j[1].biasA = b_kx; pj.j[1].biasC = b_kc; pj.j[1].lam = lam + 4096; pj.j[1].out = kg;
    pj.j[2].A = Av; pj.j[2].Bt = Wtv; pj.j[2].K = 1024;
    pj.j[2].biasA = b_vx; pj.j[2].biasC = nullptr; pj.j[2].lam = nullptr; pj.j[2].out = Pv;
    projall<<<dim3(8, 32, 3), 256, 0, stream>>>(pj);

    // 5. transpose V (Av dead -> Vtg aliases it)
    vtrans<<<dim3(64, 2, 32), 256, 0, stream>>>(Pv, Vtg);

    // 6. attention (split-K x2, 32 q/wave, G2L dbuf, in-reg P transpose)
    attn5<<<dim3(16, 32, 2), 256, 0, stream>>>(qg, kg, Vtg, ctxp, l_part);

    // 7. merge partials -> ctx bf16
    merge<<<4096, 256, 0, stream>>>(ctxp, l_part, ctxbf);

    // 8. output projection -> d_out (fp32)
    gemm64<<<dim3(8, 64), 256, 0, stream>>>(ctxbf, Wto, b_out, (float*)d_out);
}

// Round 2
// 330.861 us; speedup vs baseline: 1.0692x; 1.0389x over previous
//
#include <hip/hip_runtime.h>
#include <math.h>

typedef unsigned short u16;
typedef __attribute__((ext_vector_type(8))) short short8;     // 8 bf16 = one MFMA A/B frag
typedef __attribute__((ext_vector_type(4))) float floatx4;    // MFMA C/D frag
typedef __attribute__((ext_vector_type(4))) unsigned short ushort4v;
typedef __attribute__((ext_vector_type(2))) unsigned int uint2v;

// ---------- bf16 helpers (raw u16, RNE) ----------
__device__ __forceinline__ float bf2f(u16 x) {
    union { unsigned int u; float f; } v; v.u = ((unsigned int)x) << 16; return v.f;
}
__device__ __forceinline__ u16 f2bf(float f) {
    union { float f; unsigned int u; } v; v.f = f;
    unsigned int r = v.u + 0x7fffu + ((v.u >> 16) & 1u);
    return (u16)(r >> 16);
}
__device__ __forceinline__ unsigned int pk2bf(float a, float b) {
#if __has_builtin(__builtin_amdgcn_cvt_pk_bf16_f32)
    auto r = __builtin_amdgcn_cvt_pk_bf16_f32(a, b);
    union { decltype(r) v; unsigned int u; } cv; cv.v = r; return cv.u;
#else
    return (unsigned int)f2bf(a) | ((unsigned int)f2bf(b) << 16);
#endif
}
// bare v_exp_f32 (no OCML range-fixup wrapper); inputs bounded in this kernel
__device__ __forceinline__ float fexp2(float x) {
#if __has_builtin(__builtin_amdgcn_exp2f)
    return __builtin_amdgcn_exp2f(x);
#else
    return exp2f(x);
#endif
}

// ---------- cross-lane reg-bit <-> lane-bit swaps ----------
__device__ __forceinline__ void swap32(unsigned int& x0, unsigned int& x1, int lane) {
#if __has_builtin(__builtin_amdgcn_permlane32_swap)
    (void)lane;
    auto r = __builtin_amdgcn_permlane32_swap((int)x0, (int)x1, false, false);
    x0 = (unsigned int)r[0]; x1 = (unsigned int)r[1];
#else
    const bool hi = (lane & 32) != 0;
    const unsigned int s = hi ? x0 : x1;
    const unsigned int rr = (unsigned int)__shfl_xor((int)s, 32, 64);
    const unsigned int n0 = hi ? rr : x0;
    const unsigned int n1 = hi ? x1 : rr;
    x0 = n0; x1 = n1;
#endif
}
__device__ __forceinline__ void swap16(unsigned int& x0, unsigned int& x1, int lane) {
#if __has_builtin(__builtin_amdgcn_permlane16_swap)
    (void)lane;
    auto r = __builtin_amdgcn_permlane16_swap((int)x0, (int)x1, false, false);
    x0 = (unsigned int)r[0]; x1 = (unsigned int)r[1];
#else
    const bool hi = (lane & 16) != 0;
    const unsigned int s = hi ? x0 : x1;
    const unsigned int rr = (unsigned int)__shfl_xor((int)s, 16, 64);
    const unsigned int n0 = hi ? rr : x0;
    const unsigned int n1 = hi ? x1 : rr;
    x0 = n0; x1 = n1;
#endif
}

// async global -> LDS, 16B per lane (dst must be linear: wave base + lane*16)
__device__ __forceinline__ void g2l16(const u16* g, u16* l) {
    __builtin_amdgcn_global_load_lds(
        (const __attribute__((address_space(1))) void*)g,
        (__attribute__((address_space(3))) void*)l, 16, 0, 0);
}

// =====================================================================
// wfuse: w_z[row] = dot(W_z[row][:], wv_z[:]) ; block x==0 also emits
// bdot[z] = dot(bl_z, wv_z).  grid (64, 4).
// =====================================================================
struct WFuseJobs { const float* W[4]; const float* wv[4]; const float* bl[4];
                   float* out[4]; float* bdot; };

__global__ __launch_bounds__(256) void wfuse(WFuseJobs wf) {
    const int z = blockIdx.y;
    const float* W = wf.W[z];
    const float* wv = wf.wv[z];
    float* out = wf.out[z];
    const int t = threadIdx.x;
    const int lane = t & 63, w = t >> 6;
#pragma unroll
    for (int i = 0; i < 4; i++) {
        const int row = blockIdx.x * 16 + w * 4 + i;
        const float* Wr = W + (size_t)row * 1024 + lane * 16;
        const float* vr = wv + lane * 16;
        float p = 0.f;
#pragma unroll
        for (int c = 0; c < 4; c++) {
            const floatx4 a = *(const floatx4*)(Wr + c * 4);
            const floatx4 b = *(const floatx4*)(vr + c * 4);
            p += a[0] * b[0] + a[1] * b[1] + a[2] * b[2] + a[3] * b[3];
        }
#pragma unroll
        for (int m = 1; m <= 32; m <<= 1) p += __shfl_xor(p, m);
        if (lane == 0) out[row] = p;
    }
    if (blockIdx.x == 0) {
        const floatx4 bb = *(const floatx4*)(wf.bl[z] + t * 4);
        const floatx4 vv = *(const floatx4*)(wv + t * 4);
        float p = bb[0] * vv[0] + bb[1] * vv[1] + bb[2] * vv[2] + bb[3] * vv[3];
#pragma unroll
        for (int m = 1; m <= 32; m <<= 1) p += __shfl_xor(p, m);
        __shared__ float red[4];
        if ((t & 63) == 0) red[t >> 6] = p;
        __syncthreads();
        if (t == 0) wf.bdot[z] = red[0] + red[1] + red[2] + red[3];
    }
}

// =====================================================================
// gatecast: per row m, z<2: lam = sigmoid(xa.w1 + xc.w2 + consts);
//   write A'[m] = [(1-lam)*xa | lam*xc] bf16 (concat-K layout, stride 2048)
//   and lam[m] for the GEMM epilogue bias mix.
// z==2: plain cast vx -> bf16 (stride 1024).
// =====================================================================
struct GCJobs {
    const float* xa[3]; const float* xc[3];
    const float* w1[3]; const float* w2[3];
    const float* bdot;                 // 4 scalars
    const float* sA[3]; const float* sB[3];
    float* lamout[3];
    u16* dst[3];
};

__global__ __launch_bounds__(256) void gatecast(GCJobs gj) {
    const int z = blockIdx.y;
    const int row = blockIdx.x;
    const int t = threadIdx.x;
    const size_t off = (size_t)row * 1024 + t * 4;
    const floatx4 a = *(const floatx4*)(gj.xa[z] + off);

    if (z == 2) {
        ushort4v o;
        const unsigned int lo = pk2bf(a[0], a[1]);
        const unsigned int hi = pk2bf(a[2], a[3]);
        o[0] = (u16)(lo & 0xffff); o[1] = (u16)(lo >> 16);
        o[2] = (u16)(hi & 0xffff); o[3] = (u16)(hi >> 16);
        *(ushort4v*)(gj.dst[2] + (size_t)row * 1024 + t * 4) = o;
        return;
    }

    const floatx4 c  = *(const floatx4*)(gj.xc[z] + off);
    const floatx4 w1 = *(const floatx4*)(gj.w1[z] + t * 4);
    const floatx4 w2 = *(const floatx4*)(gj.w2[z] + t * 4);
    float p = 0.f;
#pragma unroll
    for (int j = 0; j < 4; j++) p += a[j] * w1[j] + c[j] * w2[j];
#pragma unroll
    for (int m = 1; m <= 32; m <<= 1) p += __shfl_xor(p, m);
    __shared__ float red[4];
    if ((t & 63) == 0) red[t >> 6] = p;
    __syncthreads();
    const float x = red[0] + red[1] + red[2] + red[3]
                  + gj.bdot[2 * z] + gj.bdot[2 * z + 1]
                  + gj.sA[z][0] + gj.sB[z][0];
    const float lam = 1.f / (1.f + exp2f(-x * 1.44269504f));
    if (t == 0) gj.lamout[z][row] = lam;
    const float oml = 1.f - lam;

    u16* d = gj.dst[z] + (size_t)row * 2048 + t * 4;
    ushort4v o1, o2;
    {
        const unsigned int lo = pk2bf(oml * a[0], oml * a[1]);
        const unsigned int hi = pk2bf(oml * a[2], oml * a[3]);
        o1[0] = (u16)(lo & 0xffff); o1[1] = (u16)(lo >> 16);
        o1[2] = (u16)(hi & 0xffff); o1[3] = (u16)(hi >> 16);
    }
    {
        const unsigned int lo = pk2bf(lam * c[0], lam * c[1]);
        const unsigned int hi = pk2bf(lam * c[2], lam * c[3]);
        o2[0] = (u16)(lo & 0xffff); o2[1] = (u16)(lo >> 16);
        o2[2] = (u16)(hi & 0xffff); o2[3] = (u16)(hi >> 16);
    }
    *(ushort4v*)d = o1;
    *(ushort4v*)(d + 1024) = o2;
}

// =====================================================================
// wtrans: W[k][n] fp32 -> Wt[n*stride + koff + k] bf16 (concat-K capable)
// =====================================================================
struct WTJobs { const float* src[6]; u16* dst[6]; int stride[6]; int koff[6]; };

__global__ __launch_bounds__(256) void wtrans(WTJobs wj) {
    __shared__ float tile[32][33];
    const int z = blockIdx.z;
    const float* W = wj.src[z];
    u16* Wt = wj.dst[z];
    const int stride = wj.stride[z], koff = wj.koff[z];
    const int n0 = blockIdx.x * 32, k0 = blockIdx.y * 32;
    const int tx = threadIdx.x & 31, ty = threadIdx.x >> 5;
#pragma unroll
    for (int i = 0; i < 4; i++)
        tile[ty + i * 8][tx] = W[(size_t)(k0 + ty + i * 8) * 1024 + n0 + tx];
    __syncthreads();
#pragma unroll
    for (int i = 0; i < 4; i++)
        Wt[(size_t)(n0 + ty + i * 8) * stride + koff + k0 + tx] = f2bf(tile[tx][ty + i * 8]);
}

// =====================================================================
// transpose V: V[s][base+d] (stride 2048) -> Vtg[(bh*64+d)*2048 + s], bf16
// =====================================================================
__global__ __launch_bounds__(256) void vtrans(const u16* __restrict__ V,
                                              u16* __restrict__ Vtg) {
    __shared__ u16 tile[32][34];
    const int bh = blockIdx.z, b = bh >> 4, h = bh & 15;
    const int base = b * 1024 + h * 64;
    const int s0 = blockIdx.x * 32, d0 = blockIdx.y * 32;
    const int tx = threadIdx.x & 31, ty = threadIdx.x >> 5;
#pragma unroll
    for (int i = 0; i < 4; i++)
        tile[ty + i * 8][tx] = V[(size_t)(s0 + ty + i * 8) * 2048 + base + d0 + tx];
    __syncthreads();
#pragma unroll
    for (int i = 0; i < 4; i++)
        Vtg[((size_t)bh * 64 + d0 + ty + i * 8) * 2048 + s0 + tx] = tile[tx][ty + i * 8];
}

// =====================================================================
// projall v4: T3-minimal global_load_lds pipeline (m97 structure).
// out[M,1024] = A[M,K] @ Bt[1024][K] (+ bias / lam-bias-mix epilogue,
// optional fp32 out, optional pre-softmax scale folded into bf16 out).
// 128x128 tile, BK=32, dbuf LDS 32 KB, ONE barrier per K-step.
// =====================================================================
struct PJob {
    const u16* A; const u16* Bt; int K;
    const float* biasA; const float* biasC; const float* lam;
    u16* out; float* outf; float scale;
};
struct PJobs { PJob j[4]; };

__global__ __launch_bounds__(256, 3) void projall(PJobs jobs) {
    __shared__ __align__(16) u16 As[2][128 * 32];
    __shared__ __align__(16) u16 Bs[2][128 * 32];
    const PJob jb = jobs.j[blockIdx.z];
    const int K = jb.K;
    const int m0 = blockIdx.y * 128;
    const int n0 = blockIdx.x * 128;
    const int t = threadIdx.x;
    const int lane = t & 63;
    const int wid = t >> 6;
    const int wm = wid >> 1, wn = wid & 1;
    const int qd = lane >> 4, lm = lane & 15;

    const floatx4 zero4 = {0.f, 0.f, 0.f, 0.f};
    floatx4 acc[4][4];
#pragma unroll
    for (int i = 0; i < 4; i++)
#pragma unroll
        for (int j2 = 0; j2 < 4; j2++) acc[i][j2] = zero4;

    // staging: thread t writes LDS bytes [t*16, t*16+16) of each half-tile
    // (linear => row t>>2, 16B-unit t&3 of a row-major [128][32] u16 tile).
    const u16* Ap = jb.A + (size_t)(m0 + (t >> 2)) * K + (t & 3) * 8;
    const u16* Bp = jb.Bt + (size_t)(n0 + (t >> 2)) * K + (t & 3) * 8;

#define PSTAGE(BUF, KOFF) do {                                         \
        g2l16(Ap + (KOFF),                   &As[BUF][t * 8]);         \
        g2l16(Ap + (KOFF) + (size_t)64 * K,  &As[BUF][2048 + t * 8]);  \
        g2l16(Bp + (KOFF),                   &Bs[BUF][t * 8]);         \
        g2l16(Bp + (KOFF) + (size_t)64 * K,  &Bs[BUF][2048 + t * 8]);  \
    } while (0)

    PSTAGE(0, 0);
    __syncthreads();
    int cur = 0;
    for (int k0 = 0; k0 < K; k0 += 32) {
        if (k0 + 32 < K) PSTAGE(cur ^ 1, k0 + 32);

        short8 af[4], bfg[4];
#pragma unroll
        for (int i = 0; i < 4; i++) {
            af[i]  = *(const short8*)&As[cur][(wm * 64 + i * 16 + lm) * 32 + qd * 8];
            bfg[i] = *(const short8*)&Bs[cur][(wn * 64 + i * 16 + lm) * 32 + qd * 8];
        }
#pragma unroll
        for (int i = 0; i < 4; i++)
#pragma unroll
            for (int j2 = 0; j2 < 4; j2++)
                acc[i][j2] = __builtin_amdgcn_mfma_f32_16x16x32_bf16(af[i], bfg[j2], acc[i][j2], 0, 0, 0);

        __syncthreads();   // drains prefetch vmcnt + protects dbuf WAR
        cur ^= 1;
    }
#undef PSTAGE

#pragma unroll
    for (int i = 0; i < 4; i++) {
        const int mb = m0 + wm * 64 + i * 16 + qd * 4;
        float lamv[4];
        if (jb.lam) {
#pragma unroll
            for (int r = 0; r < 4; r++) lamv[r] = jb.lam[mb + r];
        }
#pragma unroll
        for (int j2 = 0; j2 < 4; j2++) {
            const int col = n0 + wn * 64 + j2 * 16 + lm;
            const float bA = jb.biasA[col];
            if (jb.outf) {
#pragma unroll
                for (int r = 0; r < 4; r++)
                    jb.outf[(size_t)(mb + r) * 1024 + col] = acc[i][j2][r] + bA;
            } else if (jb.lam) {
                const float dB = jb.biasC[col] - bA;
#pragma unroll
                for (int r = 0; r < 4; r++)
                    jb.out[(size_t)(mb + r) * 1024 + col] =
                        f2bf((acc[i][j2][r] + bA + lamv[r] * dB) * jb.scale);
            } else {
#pragma unroll
                for (int r = 0; r < 4; r++)
                    jb.out[(size_t)(mb + r) * 1024 + col] =
                        f2bf((acc[i][j2][r] + bA) * jb.scale);
            }
        }
    }
}

// =====================================================================
// attention v6: split-K flash, VALU-lean.
//  - q pre-scaled by log2(e)/sqrt(64) in projall epilogue -> no per-score mul
//  - bare v_exp_f32 (no OCML wrapper)
//  - softmax denominator via MFMA(P, ones) -> no per-score scalar adds
//  - K/V via global_load_lds into XOR-swizzled linear LDS, dbuf, in-reg P
// =====================================================================
__global__ __launch_bounds__(256, 4) void attn6(
    const u16* __restrict__ Q, const u16* __restrict__ Kk,
    const u16* __restrict__ Vtg, float* __restrict__ ctxp,
    float* __restrict__ lp) {
    __shared__ __align__(16) u16 SB[16384];   // [2 bufs][K 64x64 | V 64x64] bf16

    // XCD-colocating bijective swizzle (nwg = 1024, 8 XCDs)
    const int bid = blockIdx.x + 16 * (blockIdx.y + 32 * blockIdx.z);
    const int sw = (bid & 7) * 128 + (bid >> 3);
    const int qt = sw & 15;
    const int bh = (sw >> 4) & 31;
    const int sp = sw >> 9;
    const int b = bh >> 4, h = bh & 15;
    const int hb = b * 1024 + h * 64;

    const int t = threadIdx.x, lane = t & 63, w = t >> 6;
    const int qd = lane >> 4, lm = lane & 15;
    const int q0w = qt * 128 + w * 32;

    // Q fragments (B operand of swapped QK^T): 2 qh blocks x 2 k-chunks
    short8 qf[2][2];
#pragma unroll
    for (int qh = 0; qh < 2; qh++) {
        const u16* qr = Q + (size_t)(q0w + qh * 16 + lm) * 2048 + hb;
#pragma unroll
        for (int c = 0; c < 2; c++)
            qf[qh][c] = *(const short8*)(qr + c * 32 + qd * 8);
    }

    const floatx4 zero4 = {0.f, 0.f, 0.f, 0.f};
    floatx4 ctx[2][4];
#pragma unroll
    for (int qh = 0; qh < 2; qh++)
#pragma unroll
        for (int g = 0; g < 4; g++) ctx[qh][g] = zero4;
    floatx4 accL[2] = {zero4, zero4};

    // all-ones bf16 B fragment for the denominator MFMA
    union { unsigned int u[4]; short8 s; } ov;
    ov.u[0] = ov.u[1] = ov.u[2] = ov.u[3] = 0x3F803F80u;
    const short8 onesb = ov.s;

    // staging: wave w stages K rows w*16.. and V rows w*16.. ; source 16B-unit
    // pre-swizzled so LDS holds unit_phys = unit_logical ^ (row&7).
    const int rl = lane >> 3;               // 0..7
    const int cuz = (lane & 7) ^ rl;        // swizzled source 16B-unit
    const u16* kp = Kk + (size_t)(sp * 1024 + w * 16 + rl) * 2048 + hb + cuz * 8;
    const u16* vp = Vtg + ((size_t)bh * 64 + w * 16 + rl) * 2048 + sp * 1024 + cuz * 8;
    u16* kd = &SB[(w * 16) * 64];
    u16* vd = &SB[4096 + (w * 16) * 64];

    // swizzled LDS read offsets (u16 units)
    const int rdA = lm * 64 + ((qd ^ (lm & 7)) << 3);   // c=0
    const int rdB = rdA ^ 32;                            // c=1 (unit ^ 4)

#define STAGE(BUF) do {                                             \
        g2l16(kp,            kd + (BUF) * 8192);                    \
        g2l16(kp + 8 * 2048, kd + (BUF) * 8192 + 8 * 64);           \
        g2l16(vp,            vd + (BUF) * 8192);                    \
        g2l16(vp + 8 * 2048, vd + (BUF) * 8192 + 8 * 64);           \
        kp += 64 * 2048; vp += 64;                                  \
    } while (0)

#define COMPUTE(BUF) do {                                                          \
        short8 pa[2][2];                                                           \
        _Pragma("unroll")                                                          \
        for (int gp = 0; gp < 2; gp++) {                                           \
            unsigned int pw[2][2][2];                                              \
            _Pragma("unroll")                                                      \
            for (int g0 = 0; g0 < 2; g0++) {                                       \
                const int g = gp * 2 + g0;                                         \
                const short8 kf0 = *(const short8*)&SB[(BUF) * 8192 + g * 1024 + rdA]; \
                const short8 kf1 = *(const short8*)&SB[(BUF) * 8192 + g * 1024 + rdB]; \
                _Pragma("unroll")                                                  \
                for (int qh = 0; qh < 2; qh++) {                                   \
                    floatx4 st = zero4;                                            \
                    st = __builtin_amdgcn_mfma_f32_16x16x32_bf16(kf0, qf[qh][0], st, 0, 0, 0); \
                    st = __builtin_amdgcn_mfma_f32_16x16x32_bf16(kf1, qf[qh][1], st, 0, 0, 0); \
                    const float e0 = fexp2(st[0]), e1 = fexp2(st[1]);              \
                    const float e2 = fexp2(st[2]), e3 = fexp2(st[3]);              \
                    pw[qh][g0][0] = pk2bf(e0, e1);                                 \
                    pw[qh][g0][1] = pk2bf(e2, e3);                                 \
                }                                                                  \
            }                                                                      \
            _Pragma("unroll")                                                      \
            for (int qh = 0; qh < 2; qh++) {                                       \
                unsigned int a0 = pw[qh][0][0], b0 = pw[qh][1][0];                 \
                unsigned int a1 = pw[qh][0][1], b1 = pw[qh][1][1];                 \
                swap32(a0, b0, lane); swap32(a1, b1, lane);                        \
                swap16(a0, b0, lane); swap16(a1, b1, lane);                        \
                union { unsigned int u[4]; short8 s; } cv;                         \
                cv.u[0] = a0; cv.u[1] = a1; cv.u[2] = b0; cv.u[3] = b1;            \
                pa[qh][gp] = cv.s;                                                 \
            }                                                                      \
        }                                                                          \
        __builtin_amdgcn_s_setprio(1);                                             \
        _Pragma("unroll")                                                          \
        for (int g = 0; g < 4; g++) {                                              \
            const short8 vb0 = *(const short8*)&SB[(BUF) * 8192 + 4096 + g * 1024 + rdA]; \
            const short8 vb1 = *(const short8*)&SB[(BUF) * 8192 + 4096 + g * 1024 + rdB]; \
            _Pragma("unroll")                                                      \
            for (int qh = 0; qh < 2; qh++) {                                       \
                ctx[qh][g] = __builtin_amdgcn_mfma_f32_16x16x32_bf16(pa[qh][0], vb0, ctx[qh][g], 0, 0, 0); \
                ctx[qh][g] = __builtin_amdgcn_mfma_f32_16x16x32_bf16(pa[qh][1], vb1, ctx[qh][g], 0, 0, 0); \
            }                                                                      \
        }                                                                          \
        _Pragma("unroll")                                                          \
        for (int qh = 0; qh < 2; qh++) {                                           \
            accL[qh] = __builtin_amdgcn_mfma_f32_16x16x32_bf16(pa[qh][0], onesb, accL[qh], 0, 0, 0); \
            accL[qh] = __builtin_amdgcn_mfma_f32_16x16x32_bf16(pa[qh][1], onesb, accL[qh], 0, 0, 0); \
        }                                                                          \
        __builtin_amdgcn_s_setprio(0);                                             \
    } while (0)

    STAGE(0);   // prologue: kt = 0 -> buf0
#pragma unroll 1
    for (int it = 0; it < 8; it++) {
        __syncthreads();            // buf0 ready (vmcnt drained); buf1 reads done
        STAGE(1);                   // prefetch kt = 2*it+1 -> buf1
        COMPUTE(0);                 // kt = 2*it from buf0
        __syncthreads();            // buf1 ready; buf0 reads done
        if (it < 7) STAGE(0);       // prefetch kt = 2*it+2 -> buf0
        COMPUTE(1);                 // kt = 2*it+1 from buf1
    }
#undef STAGE
#undef COMPUTE

    float* cbase = ctxp + (size_t)sp * 4194304;
#pragma unroll
    for (int qh = 0; qh < 2; qh++) {
        if (lm == 0) {
#pragma unroll
            for (int r = 0; r < 4; r++)
                lp[(size_t)sp * 65536 + bh * 2048 + q0w + qh * 16 + qd * 4 + r] = accL[qh][r];
        }
#pragma unroll
        for (int r = 0; r < 4; r++) {
            const int srow = q0w + qh * 16 + qd * 4 + r;
            float* orow = cbase + (size_t)srow * 2048 + hb;
#pragma unroll
            for (int g = 0; g < 4; g++)
                orow[g * 16 + lm] = ctx[qh][g][r];
        }
    }
}

// =====================================================================
// merge: out_bf16 = (ctx0 + ctx1) / (l0 + l1), elementwise over 4M
// =====================================================================
__global__ __launch_bounds__(256) void merge(const float* __restrict__ ctxp,
                                             const float* __restrict__ lp,
                                             u16* __restrict__ out) {
    const size_t idx = ((size_t)blockIdx.x * 256 + threadIdx.x) * 4;
    const floatx4 a = *(const floatx4*)(ctxp + idx);
    const floatx4 c = *(const floatx4*)(ctxp + 4194304 + idx);
    const int srow = (int)(idx >> 11);
    const int rem = (int)(idx & 2047);
    const int bh = rem >> 6;
    const float l = lp[bh * 2048 + srow] + lp[65536 + bh * 2048 + srow];
    const float inv = 1.0f / l;
    ushort4v o;
    const unsigned int lo = pk2bf((a[0] + c[0]) * inv, (a[1] + c[1]) * inv);
    const unsigned int hi = pk2bf((a[2] + c[2]) * inv, (a[3] + c[3]) * inv);
    o[0] = (u16)(lo & 0xffff); o[1] = (u16)(lo >> 16);
    o[2] = (u16)(hi & 0xffff); o[3] = (u16)(hi >> 16);
    *(ushort4v*)(out + idx) = o;
}

// =====================================================================
// host orchestration
// =====================================================================
extern "C" void kernel_launch(void* const* d_in, const int* in_sizes, int n_in,
                              void* d_out, int out_size, void* d_ws, size_t ws_size,
                              hipStream_t stream) {
    const float* qx = (const float*)d_in[0];
    const float* kx = (const float*)d_in[1];
    const float* vx = (const float*)d_in[2];
    const float* qc = (const float*)d_in[3];
    const float* kc = (const float*)d_in[4];
    const float* W_qx = (const float*)d_in[5];   const float* b_qx = (const float*)d_in[6];
    const float* W_kx = (const float*)d_in[7];   const float* b_kx = (const float*)d_in[8];
    const float* W_vx = (const float*)d_in[9];   const float* b_vx = (const float*)d_in[10];
    const float* W_qc = (const float*)d_in[11];  const float* b_qc = (const float*)d_in[12];
    const float* W_kc = (const float*)d_in[13];  const float* b_kc = (const float*)d_in[14];
    const float* W_out = (const float*)d_in[15]; const float* b_out = (const float*)d_in[16];
    const float* W_Vqx = (const float*)d_in[17]; const float* b_Vqx = (const float*)d_in[18];
    const float* W_Vqc = (const float*)d_in[19]; const float* b_Vqc = (const float*)d_in[20];
    const float* W_Vkx = (const float*)d_in[21]; const float* b_Vkx = (const float*)d_in[22];
    const float* W_Vkc = (const float*)d_in[23]; const float* b_Vkc = (const float*)d_in[24];

    char* ws = (char*)d_ws;
    const size_t MB = 1048576;
    u16* Aq  = (u16*)ws;
    u16* Ak  = (u16*)(ws + 16 * MB);
    u16* Av  = (u16*)(ws + 32 * MB);
    u16* Wtq = (u16*)(ws + 40 * MB);
    u16* Wtk = (u16*)(ws + 44 * MB);
    u16* Wtv = (u16*)(ws + 48 * MB);
    u16* Wto = (u16*)(ws + 50 * MB);
    u16* Pv    = (u16*)(ws + 52 * MB);
    u16* qg    = (u16*)(ws + 60 * MB);
    u16* kg    = (u16*)(ws + 68 * MB);
    u16* ctxbf = (u16*)(ws + 76 * MB);
    float* wfused = (float*)(ws + 84 * MB);                       // 4 x 1024
    float* bdot   = (float*)(ws + 84 * MB + 16384);               // 4 scalars
    float* lam    = (float*)(ws + 84 * MB + 16384 + 256);         // 2 x 4096
    float* l_part = (float*)(ws + 84 * MB + 16384 + 256 + 32768); // 2 x 32 x 2048
    float* ctxp = (float*)ws;                  // aliases Aq/Ak (dead after projall)
    u16* Vtg    = (u16*)(ws + 32 * MB);        // aliases Av (dead after projall)

    // 1. fused gating weight vectors + bias-dot consts
    WFuseJobs wf;
    wf.W[0] = W_qx; wf.wv[0] = W_Vqx; wf.bl[0] = b_qx; wf.out[0] = wfused;
    wf.W[1] = W_qc; wf.wv[1] = W_Vqc; wf.bl[1] = b_qc; wf.out[1] = wfused + 1024;
    wf.W[2] = W_kx; wf.wv[2] = W_Vkx; wf.bl[2] = b_kx; wf.out[2] = wfused + 2048;
    wf.W[3] = W_kc; wf.wv[3] = W_Vkc; wf.bl[3] = b_kc; wf.out[3] = wfused + 3072;
    wf.bdot = bdot;
    wfuse<<<dim3(64, 4), 256, 0, stream>>>(wf);

    // 2. gatecast: lambdas + scaled concat-K bf16 A matrices + v cast
    GCJobs gj;
    gj.xa[0] = qx; gj.xc[0] = qc; gj.w1[0] = wfused;        gj.w2[0] = wfused + 1024;
    gj.sA[0] = b_Vqx; gj.sB[0] = b_Vqc; gj.lamout[0] = lam;        gj.dst[0] = Aq;
    gj.xa[1] = kx; gj.xc[1] = kc; gj.w1[1] = wfused + 2048; gj.w2[1] = wfused + 3072;
    gj.sA[1] = b_Vkx; gj.sB[1] = b_Vkc; gj.lamout[1] = lam + 4096; gj.dst[1] = Ak;
    gj.xa[2] = vx; gj.xc[2] = nullptr; gj.w1[2] = nullptr; gj.w2[2] = nullptr;
    gj.sA[2] = nullptr; gj.sB[2] = nullptr; gj.lamout[2] = nullptr; gj.dst[2] = Av;
    gj.bdot = bdot;
    gatecast<<<dim3(4096, 3), 256, 0, stream>>>(gj);

    // 3. transpose + cast weights into concat-K layouts
    WTJobs wj;
    wj.src[0] = W_qx; wj.dst[0] = Wtq; wj.stride[0] = 2048; wj.koff[0] = 0;
    wj.src[1] = W_qc; wj.dst[1] = Wtq; wj.stride[1] = 2048; wj.koff[1] = 1024;
    wj.src[2] = W_kx; wj.dst[2] = Wtk; wj.stride[2] = 2048; wj.koff[2] = 0;
    wj.src[3] = W_kc; wj.dst[3] = Wtk; wj.stride[3] = 2048; wj.koff[3] = 1024;
    wj.src[4] = W_vx; wj.dst[4] = Wtv; wj.stride[4] = 1024; wj.koff[4] = 0;
    wj.src[5] = W_out; wj.dst[5] = Wto; wj.stride[5] = 1024; wj.koff[5] = 0;
    wtrans<<<dim3(32, 32, 6), 256, 0, stream>>>(wj);

    // 4. projections: q (K=2048, pre-scaled by log2e/8), k (K=2048), v (K=1024)
    const float QSCALE = 0.18033688011112042f;   // log2(e)/sqrt(64)
    PJobs pj;
    pj.j[0].A = Aq; pj.j[0].Bt = Wtq; pj.j[0].K = 2048;
    pj.j[0].biasA = b_qx; pj.j[0].biasC = b_qc; pj.j[0].lam = lam;
    pj.j[0].out = qg; pj.j[0].outf = nullptr; pj.j[0].scale = QSCALE;
    pj.j[1].A = Ak; pj.j[1].Bt = Wtk; pj.j[1].K = 2048;
    pj.j[1].biasA = b_kx; pj.j[1].biasC = b_kc; pj.j[1].lam = lam + 4096;
    pj.j[1].out = kg; pj.j[1].outf = nullptr; pj.j[1].scale = 1.0f;
    pj.j[2].A = Av; pj.j[2].Bt = Wtv; pj.j[2].K = 1024;
    pj.j[2].biasA = b_vx; pj.j[2].biasC = nullptr; pj.j[2].lam = nullptr;
    pj.j[2].out = Pv; pj.j[2].outf = nullptr; pj.j[2].scale = 1.0f;
    pj.j[3] = pj.j[2];
    projall<<<dim3(8, 32, 3), 256, 0, stream>>>(pj);

    // 5. transpose V (Av dead -> Vtg aliases it)
    vtrans<<<dim3(64, 2, 32), 256, 0, stream>>>(Pv, Vtg);

    // 6. attention (split-K x2, 32 q/wave, G2L dbuf, in-reg P, MFMA denom)
    attn6<<<dim3(16, 32, 2), 256, 0, stream>>>(qg, kg, Vtg, ctxp, l_part);

    // 7. merge partials -> ctx bf16
    merge<<<4096, 256, 0, stream>>>(ctxp, l_part, ctxbf);

    // 8. output projection -> d_out (fp32) via projall (fp32 epilogue job)
    PJobs po;
    po.j[0].A = ctxbf; po.j[0].Bt = Wto; po.j[0].K = 1024;
    po.j[0].biasA = b_out; po.j[0].biasC = nullptr; po.j[0].lam = nullptr;
    po.j[0].out = nullptr; po.j[0].outf = (float*)d_out; po.j[0].scale = 1.0f;
    po.j[1] = po.j[0]; po.j[2] = po.j[0]; po.j[3] = po.j[0];
    projall<<<dim3(8, 32, 1), 256, 0, stream>>>(po);
}